// Round 1
// 661.880 us; speedup vs baseline: 1.0602x; 1.0602x over previous
//
#include <hip/hip_runtime.h>
#include <math.h>

#define BATCH 512
#define DIM 256
#define HEADS 4
#define KD 16
#define VD 64
#define NQ 196
#define CHW (DIM * NQ)   // 50176

typedef __attribute__((ext_vector_type(8))) short short8;
typedef __attribute__((ext_vector_type(4))) float f32x4;

#define MFMA16(A, B, C) __builtin_amdgcn_mfma_f32_16x16x32_bf16((A), (B), (C), 0, 0, 0)

__device__ __forceinline__ unsigned short f2bf(float f) {
    unsigned int u = __float_as_uint(f);
    u += 0x7FFFu + ((u >> 16) & 1u);          // round-to-nearest-even
    return (unsigned short)(u >> 16);
}
__device__ __forceinline__ float bf2f(unsigned short h) {
    return __uint_as_float(((unsigned int)h) << 16);
}
// load 8 consecutive floats, emit bf16 hi + lo-correction fragments
__device__ __forceinline__ void split8(const float* __restrict__ p, short8& hi, short8& lo) {
    float v[8];
    *(float4*)&v[0] = *(const float4*)p;
    *(float4*)&v[4] = *(const float4*)(p + 4);
    #pragma unroll
    for (int j = 0; j < 8; ++j) {
        unsigned short h = f2bf(v[j]);
        hi[j] = (short)h;
        lo[j] = (short)f2bf(v[j] - bf2f(h));
    }
}

// ---------------- LDS layout (bytes) ----------------
// union region: feat bf16 [208][72]  (29952 B)  OVERLAID BY  qc hi/lo [208][40] (33280 B)
#define OFF_QCH   0
#define OFF_QCL   16640
#define OFF_QRAW  33280      // fp32 [16][208] = 13312
#define OFF_KBH   46592      // bf16 [224][40] = 17920
#define OFF_KBL   64512
#define OFF_VBH   82432      // bf16 [64][232] = 29696
#define OFF_VBL   112128
#define OFF_P     141824     // bf16 [208][40] = 16640
#define OFF_DEN4  158464     // fp32 [208][4]  = 3328
#define OFF_SB    161792     // fp32 [96]
#define OFF_TB    162176     // fp32 [96]
#define OFF_DWS   162560     // fp32 [16]
#define OFF_DWT   162624     // fp32 [16]
#define SMEM_BYTES 162688    // <= 163840

// -------------------- kernel 0: expand relative-position bias --------------------
__global__ __launch_bounds__(256)
void bias_expand_kernel(const float* __restrict__ attn_biases,
                        const int* __restrict__ bias_idxs,
                        float* __restrict__ biasg) {
    int i = blockIdx.x * 256 + threadIdx.x;
    const int total = HEADS * NQ * NQ;
    if (i < total) {
        int h = i / (NQ * NQ);
        int r = i - h * (NQ * NQ);
        biasg[i] = attn_biases[h * NQ + bias_idxs[r]];
    }
}

// -------------------- kernel 1: fused cascaded attention, MFMA --------------------
__global__ __launch_bounds__(1024, 4)
void cascade_attn_kernel(const float* __restrict__ x,
                         const float* __restrict__ qkv_w,
                         const float* __restrict__ qkv_g,
                         const float* __restrict__ qkv_b,
                         const float* __restrict__ qkv_rm,
                         const float* __restrict__ qkv_rv,
                         const float* __restrict__ dw_w,
                         const float* __restrict__ dw_g,
                         const float* __restrict__ dw_b,
                         const float* __restrict__ dw_rm,
                         const float* __restrict__ dw_rv,
                         const float* __restrict__ biasg,
                         unsigned short* __restrict__ yrelu) {
    extern __shared__ __align__(16) char smem[];
    unsigned short* featU = (unsigned short*)(smem + OFF_QCH);  // [208][72] (overlaid by qc)
    unsigned short* qcH   = (unsigned short*)(smem + OFF_QCH);  // [208][40]
    unsigned short* qcL   = (unsigned short*)(smem + OFF_QCL);
    float*          qraw  = (float*)(smem + OFF_QRAW);          // [16][208]
    unsigned short* kbH   = (unsigned short*)(smem + OFF_KBH);  // [224][40]
    unsigned short* kbL   = (unsigned short*)(smem + OFF_KBL);
    unsigned short* vbH   = (unsigned short*)(smem + OFF_VBH);  // [64][232]
    unsigned short* vbL   = (unsigned short*)(smem + OFF_VBL);
    unsigned short* Pb    = (unsigned short*)(smem + OFF_P);    // [208][40]
    float*          den4  = (float*)(smem + OFF_DEN4);          // [208][4]
    float*          sbT   = (float*)(smem + OFF_SB);
    float*          tbT   = (float*)(smem + OFF_TB);
    float*          dwsT  = (float*)(smem + OFF_DWS);
    float*          dwtT  = (float*)(smem + OFF_DWT);

    const int b    = blockIdx.x;
    const int tid  = threadIdx.x;
    const int w    = tid >> 6;
    const int li   = tid & 15;
    const int quad = (tid >> 4) & 3;

    // ---- init: zero ALL of LDS (pads must be exactly 0 for MFMA k-padding) ----
    for (int t = tid; t < SMEM_BYTES / 4; t += 1024) ((unsigned int*)smem)[t] = 0u;
    __syncthreads();
    // feat = bf16(x chunk 0), layout [n][72c]
    for (int t = tid; t < VD * NQ; t += 1024) {
        int n = t % NQ, c = t / NQ;
        featU[n * 72 + c] = f2bf(x[((size_t)b * DIM + c) * NQ + n]);
    }
    __syncthreads();

    for (int h = 0; h < HEADS; ++h) {
        // ---- prologue: fold BN into (s,t) tables ----
        if (tid < 96) {
            float s = qkv_g[h * 96 + tid] * rsqrtf(qkv_rv[h * 96 + tid] + 1e-5f);
            sbT[tid] = s;
            tbT[tid] = qkv_b[h * 96 + tid] - qkv_rm[h * 96 + tid] * s;
        } else if (tid < 112) {
            int c = tid - 96;
            float s = dw_g[h * 16 + c] * rsqrtf(dw_rv[h * 16 + c] + 1e-5f);
            dwsT[c] = s;
            dwtT[c] = dw_b[h * 16 + c] - dw_rm[h * 16 + c] * s;
        }
        __syncthreads();

        // ---- phase B: QKV = W(hi+lo) x feat(bf16), MFMA, folded BN ----
        // tiles: 6 o-tiles x 13 n-tiles = 78
        for (int T = w; T < 78; T += 16) {
            int ot = T / 13, nt = T - ot * 13;
            const float* wrow = qkv_w + ((size_t)h * 96 + ot * 16 + li) * 64;
            short8 ah0, al0, ah1, al1;
            split8(wrow + quad * 8, ah0, al0);
            split8(wrow + 32 + quad * 8, ah1, al1);
            short8 b0 = *(const short8*)(featU + (nt * 16 + li) * 72 + quad * 8);
            short8 b1 = *(const short8*)(featU + (nt * 16 + li) * 72 + 32 + quad * 8);
            f32x4 acc = {0.f, 0.f, 0.f, 0.f};
            acc = MFMA16(ah0, b0, acc);
            acc = MFMA16(al0, b0, acc);
            acc = MFMA16(ah1, b1, acc);
            acc = MFMA16(al1, b1, acc);
            int n = nt * 16 + li;
            bool nok = (n < NQ);
            #pragma unroll
            for (int r = 0; r < 4; ++r) {
                int o = ot * 16 + quad * 4 + r;
                float val = acc[r] * sbT[o] + tbT[o];
                if (nok) {
                    if (o < 16) {
                        qraw[o * 208 + n] = val;
                    } else if (o < 32) {
                        int c = o - 16;
                        unsigned short hh = f2bf(val);
                        kbH[n * 40 + c] = hh;
                        kbL[n * 40 + c] = f2bf(val - bf2f(hh));
                    } else {
                        int d = o - 32;
                        unsigned short hh = f2bf(val);
                        vbH[d * 232 + n] = hh;
                        vbL[d * 232 + n] = f2bf(val - bf2f(hh));
                    }
                }
            }
        }
        __syncthreads();

        // ---- phase C: depthwise 5x5 conv + BN + *0.25, write qc hi/lo; zero pads ----
        for (int t = tid; t < KD * NQ; t += 1024) {
            int n = t % NQ, c = t / NQ;
            int py = n / 14, px = n - py * 14;
            const float* qr = qraw + c * 208;
            const float* wdc = dw_w + ((size_t)h * KD + c) * 25;
            float accv = 0.f;
            #pragma unroll
            for (int ky = 0; ky < 5; ++ky) {
                int yy = py + ky - 2;
                if (yy < 0 || yy >= 14) continue;
                #pragma unroll
                for (int kx = 0; kx < 5; ++kx) {
                    int xx = px + kx - 2;
                    if (xx < 0 || xx >= 14) continue;
                    accv = fmaf(wdc[ky * 5 + kx], qr[yy * 14 + xx], accv);
                }
            }
            float val = fmaf(accv, dwsT[c], dwtT[c]) * 0.25f;
            unsigned short hh = f2bf(val);
            qcH[n * 40 + c] = hh;
            qcL[n * 40 + c] = f2bf(val - bf2f(hh));
            // re-zero k-pad cols 16..31 (dirtied by feat overlay)
            qcH[n * 40 + 16 + c] = 0;
            qcL[n * 40 + 16 + c] = 0;
        }
        if (tid < 832) den4[tid] = 0.f;
        __syncthreads();

        // ---- phase D: attention. m-loop over 7 tiles of 32 keys ----
        f32x4 pacc[4];
        #pragma unroll
        for (int s = 0; s < 4; ++s) pacc[s] = (f32x4){0.f, 0.f, 0.f, 0.f};

        for (int mi = 0; mi < 7; ++mi) {
            // S-pass: 26 tiles (13 n-tiles x 2 m-subtiles); S = Q(hi+lo) x K(hi+lo), drop lo*lo
            for (int T = w; T < 26; T += 16) {
                int s = (T >= 13) ? 1 : 0;
                int nt = T - s * 13;
                int n0 = nt * 16;
                int mg = mi * 32 + s * 16 + li;       // global key index (= kb row)
                float bias4[4];
                #pragma unroll
                for (int r = 0; r < 4; ++r) {
                    int n = n0 + quad * 4 + r;
                    int ni = n < NQ ? n : NQ - 1;
                    int mgi = mg < NQ ? mg : NQ - 1;
                    bias4[r] = biasg[(size_t)h * (NQ * NQ) + ni * NQ + mgi];
                }
                short8 qh = *(const short8*)(qcH + (n0 + li) * 40 + quad * 8);
                short8 ql = *(const short8*)(qcL + (n0 + li) * 40 + quad * 8);
                short8 kh = *(const short8*)(kbH + mg * 40 + quad * 8);
                short8 kl = *(const short8*)(kbL + mg * 40 + quad * 8);
                f32x4 acc = {0.f, 0.f, 0.f, 0.f};
                acc = MFMA16(qh, kh, acc);
                acc = MFMA16(qh, kl, acc);
                acc = MFMA16(ql, kh, acc);
                bool mok = (mg < NQ);
                #pragma unroll
                for (int r = 0; r < 4; ++r) {
                    float e = mok ? __expf(acc[r] + bias4[r]) : 0.f;
                    int n = n0 + quad * 4 + r;
                    Pb[n * 40 + s * 16 + li] = f2bf(e);
                }
            }
            __syncthreads();

            // den-pass: accumulate row sums of the *bf16* P actually fed to MFMA
            if (tid < 832) {
                int n = tid >> 2, part = tid & 3;
                short8 pv = *(const short8*)(Pb + n * 40 + part * 8);
                float sum = 0.f;
                #pragma unroll
                for (int j = 0; j < 8; ++j) sum += bf2f((unsigned short)pv[j]);
                den4[n * 4 + part] += sum;
            }
            // PV: out += P x V(hi+lo); 52 tiles (13 n x 4 d), K=32 per m-iter
            {
                int slot = 0;
                for (int T = w; T < 52; T += 16, ++slot) {
                    int dt = T / 13, nt = T - dt * 13;
                    short8 p  = *(const short8*)(Pb + (nt * 16 + li) * 40 + quad * 8);
                    short8 vh = *(const short8*)(vbH + (dt * 16 + li) * 232 + mi * 32 + quad * 8);
                    short8 vl = *(const short8*)(vbL + (dt * 16 + li) * 232 + mi * 32 + quad * 8);
                    pacc[slot] = MFMA16(p, vh, pacc[slot]);
                    pacc[slot] = MFMA16(p, vl, pacc[slot]);
                }
            }
            __syncthreads();
        }

        // ---- PV epilogue: normalize, write new feat (bf16) ----
        {
            int slot = 0;
            for (int T = w; T < 52; T += 16, ++slot) {
                int dt = T / 13, nt = T - dt * 13;
                int d = dt * 16 + li;
                #pragma unroll
                for (int r = 0; r < 4; ++r) {
                    int n = nt * 16 + quad * 4 + r;
                    if (n < NQ) {
                        f32x4 dv = *(const f32x4*)(den4 + n * 4);
                        float dn = (dv.x + dv.y) + (dv.z + dv.w);
                        float val = pacc[slot][r] / dn;
                        featU[n * 72 + d] = f2bf(val);
                    }
                }
            }
        }
        __syncthreads();

        // ---- yrelu write: vectorized short8, NEW layout [b*NQ + n][256] ----
        for (int t = tid; t < (VD * NQ) / 8; t += 1024) {
            int n  = t >> 3;
            int c0 = (t & 7) * 8;
            short8 u = *(const short8*)(featU + n * 72 + c0);
            short8 ru;
            #pragma unroll
            for (int j = 0; j < 8; ++j) {
                unsigned short uu = (unsigned short)u[j];
                ru[j] = (short)((uu & 0x8000u) ? (unsigned short)0 : uu);
            }
            *(short8*)(yrelu + ((size_t)b * NQ + n) * DIM + h * VD + c0) = ru;
        }
        __syncthreads();

        // ---- cascade add for next head (x reads stay n-fastest = coalesced) ----
        if (h < 3) {
            for (int t = tid; t < VD * NQ; t += 1024) {
                int n = t % NQ, c = t / NQ;
                float v = bf2f(featU[n * 72 + c]) + x[((size_t)b * DIM + (h + 1) * VD + c) * NQ + n];
                featU[n * 72 + c] = f2bf(v);
            }
            // re-zero feat pad rows 196..207 (dirtied by qc overlay)
            for (int t = tid; t < 12 * 64; t += 1024)
                featU[(NQ + t / 64) * 72 + (t & 63)] = 0;
        }
        __syncthreads();
    }
}

// -------------------- kernel 2: projection GEMM (MFMA) + folded BN ----------------
// X layout is now [j = b*196+n][256 c] bf16 -> MFMA B-fragments load directly from
// global as 16-B dwordx4 (no LDS, no barriers). W/biasg reuse lands in L2/L3.
// block: 512 thr (8 waves), tile 64o x 256j, K=256 in 8 steps of 32
__global__ __launch_bounds__(512, 4)
void proj_kernel(const unsigned short* __restrict__ X,  // yrelu bf16 [B*NQ][256]
                 const float* __restrict__ W,           // [256][256] (o,c)
                 const float* __restrict__ pg,
                 const float* __restrict__ pb,
                 const float* __restrict__ prm,
                 const float* __restrict__ prv,
                 float* __restrict__ out) {
    const int tid  = threadIdx.x;
    const int w    = tid >> 6;
    const int li   = tid & 15;
    const int quad = (tid >> 4) & 3;
    const int jb   = blockIdx.x * 256;
    const int o0   = blockIdx.y * 64 + (w & 3) * 16;
    const int jt0  = (w >> 2) * 8;

    f32x4 acc[8];
    #pragma unroll
    for (int i = 0; i < 8; ++i) acc[i] = (f32x4){0.f, 0.f, 0.f, 0.f};

    const unsigned short* xb = X + (size_t)(jb + jt0 * 16 + li) * 256 + quad * 8;
    const float* wbase = W + (o0 + li) * 256;

    #pragma unroll 2
    for (int ks = 0; ks < 8; ++ks) {
        short8 bx[8];
        #pragma unroll
        for (int jt = 0; jt < 8; ++jt)
            bx[jt] = *(const short8*)(xb + jt * (16 * 256) + ks * 32);
        short8 ah, al;
        split8(wbase + ks * 32 + quad * 8, ah, al);
        #pragma unroll
        for (int jt = 0; jt < 8; ++jt) {
            acc[jt] = MFMA16(ah, bx[jt], acc[jt]);
            acc[jt] = MFMA16(al, bx[jt], acc[jt]);
        }
    }

    // epilogue: BN + store fp32 (output stays [b][o][n])
    #pragma unroll
    for (int r = 0; r < 4; ++r) {
        int o = o0 + quad * 4 + r;
        float s = pg[o] * rsqrtf(prv[o] + 1e-5f);
        float t = pb[o] - prm[o] * s;
        #pragma unroll
        for (int jt = 0; jt < 8; ++jt) {
            int j = jb + (jt0 + jt) * 16 + li;
            int bb = j / NQ;
            int n = j - bb * NQ;
            out[(size_t)bb * CHW + (size_t)o * NQ + n] = fmaf(acc[jt][r], s, t);
        }
    }
}

// -------------------- launch --------------------
extern "C" void kernel_launch(void* const* d_in, const int* in_sizes, int n_in,
                              void* d_out, int out_size, void* d_ws, size_t ws_size,
                              hipStream_t stream) {
    const float* x        = (const float*)d_in[0];
    const float* qkv_w    = (const float*)d_in[1];
    const float* qkv_g    = (const float*)d_in[2];
    const float* qkv_b    = (const float*)d_in[3];
    const float* qkv_rm   = (const float*)d_in[4];
    const float* qkv_rv   = (const float*)d_in[5];
    const float* dw_w     = (const float*)d_in[6];
    const float* dw_g     = (const float*)d_in[7];
    const float* dw_b     = (const float*)d_in[8];
    const float* dw_rm    = (const float*)d_in[9];
    const float* dw_rv    = (const float*)d_in[10];
    const float* proj_w   = (const float*)d_in[11];
    const float* proj_g   = (const float*)d_in[12];
    const float* proj_b   = (const float*)d_in[13];
    const float* proj_rm  = (const float*)d_in[14];
    const float* proj_rv  = (const float*)d_in[15];
    const float* attn_bs  = (const float*)d_in[16];
    const int*   bias_idx = (const int*)d_in[17];

    float* biasg = (float*)d_ws;                                   // 153664 fp32
    unsigned short* yrelu = (unsigned short*)((char*)d_ws + 614656); // B*NQ*DIM bf16, [j][c]

    {
        int total = HEADS * NQ * NQ;
        hipLaunchKernelGGL(bias_expand_kernel, dim3((total + 255) / 256), dim3(256),
                           0, stream, attn_bs, bias_idx, biasg);
    }
    hipLaunchKernelGGL(cascade_attn_kernel, dim3(BATCH), dim3(1024),
                       SMEM_BYTES, stream,
                       x, qkv_w, qkv_g, qkv_b, qkv_rm, qkv_rv,
                       dw_w, dw_g, dw_b, dw_rm, dw_rv, biasg, yrelu);
    hipLaunchKernelGGL(proj_kernel, dim3(392, 4), dim3(512), 0, stream,
                       yrelu, proj_w, proj_g, proj_b, proj_rm, proj_rv,
                       (float*)d_out);
}

// Round 2
// 597.787 us; speedup vs baseline: 1.1738x; 1.1072x over previous
//
#include <hip/hip_runtime.h>
#include <math.h>

#define BATCH 512
#define DIM 256
#define HEADS 4
#define KD 16
#define VD 64
#define NQ 196
#define CHW (DIM * NQ)   // 50176

typedef __attribute__((ext_vector_type(8))) short short8;
typedef __attribute__((ext_vector_type(4))) float f32x4;

#define MFMA16(A, B, C) __builtin_amdgcn_mfma_f32_16x16x32_bf16((A), (B), (C), 0, 0, 0)

__device__ __forceinline__ unsigned short f2bf(float f) {
    unsigned int u = __float_as_uint(f);
    u += 0x7FFFu + ((u >> 16) & 1u);          // round-to-nearest-even
    return (unsigned short)(u >> 16);
}
__device__ __forceinline__ float bf2f(unsigned short h) {
    return __uint_as_float(((unsigned int)h) << 16);
}
// load 8 consecutive floats, emit bf16 hi + lo-correction fragments
__device__ __forceinline__ void split8(const float* __restrict__ p, short8& hi, short8& lo) {
    float v[8];
    *(float4*)&v[0] = *(const float4*)p;
    *(float4*)&v[4] = *(const float4*)(p + 4);
    #pragma unroll
    for (int j = 0; j < 8; ++j) {
        unsigned short h = f2bf(v[j]);
        hi[j] = (short)h;
        lo[j] = (short)f2bf(v[j] - bf2f(h));
    }
}

// ---------------- LDS layout (bytes) ----------------
// union region: feat bf16 [208][72]  (29952 B)  OVERLAID BY  qc hi/lo [208][40] (33280 B)
#define OFF_QCH   0
#define OFF_QCL   16640
#define OFF_QRAW  33280      // fp32 [16][208] = 13312
#define OFF_KBH   46592      // bf16 [224][40] = 17920
#define OFF_KBL   64512
#define OFF_VBH   82432      // bf16 [64][232] = 29696
#define OFF_VBL   112128
#define OFF_P     141824     // bf16 [208][40] = 16640
#define OFF_DEN4  158464     // fp32 [208][4]  = 3328
#define OFF_SB    161792     // fp32 [96]
#define OFF_TB    162176     // fp32 [96]
#define OFF_DWS   162560     // fp32 [16]
#define OFF_DWT   162624     // fp32 [16]
#define SMEM_BYTES 162688    // <= 163840

// -------------------- kernel 0: expand relative-position bias --------------------
__global__ __launch_bounds__(256)
void bias_expand_kernel(const float* __restrict__ attn_biases,
                        const int* __restrict__ bias_idxs,
                        float* __restrict__ biasg) {
    int i = blockIdx.x * 256 + threadIdx.x;
    const int total = HEADS * NQ * NQ;
    if (i < total) {
        int h = i / (NQ * NQ);
        int r = i - h * (NQ * NQ);
        biasg[i] = attn_biases[h * NQ + bias_idxs[r]];
    }
}

// -------------------- kernel 1: fused cascaded attention, MFMA --------------------
__global__ __launch_bounds__(1024, 4)
void cascade_attn_kernel(const float* __restrict__ x,
                         const float* __restrict__ qkv_w,
                         const float* __restrict__ qkv_g,
                         const float* __restrict__ qkv_b,
                         const float* __restrict__ qkv_rm,
                         const float* __restrict__ qkv_rv,
                         const float* __restrict__ dw_w,
                         const float* __restrict__ dw_g,
                         const float* __restrict__ dw_b,
                         const float* __restrict__ dw_rm,
                         const float* __restrict__ dw_rv,
                         const float* __restrict__ biasg,
                         unsigned short* __restrict__ yrelu) {
    extern __shared__ __align__(16) char smem[];
    unsigned short* featU = (unsigned short*)(smem + OFF_QCH);  // [208][72] (overlaid by qc)
    unsigned short* qcH   = (unsigned short*)(smem + OFF_QCH);  // [208][40]
    unsigned short* qcL   = (unsigned short*)(smem + OFF_QCL);
    float*          qraw  = (float*)(smem + OFF_QRAW);          // [16][208]
    unsigned short* kbH   = (unsigned short*)(smem + OFF_KBH);  // [224][40]
    unsigned short* kbL   = (unsigned short*)(smem + OFF_KBL);
    unsigned short* vbH   = (unsigned short*)(smem + OFF_VBH);  // [64][232]
    unsigned short* vbL   = (unsigned short*)(smem + OFF_VBL);
    unsigned short* Pb    = (unsigned short*)(smem + OFF_P);    // [208][40]
    float*          den4  = (float*)(smem + OFF_DEN4);          // [208][4]
    float*          sbT   = (float*)(smem + OFF_SB);
    float*          tbT   = (float*)(smem + OFF_TB);
    float*          dwsT  = (float*)(smem + OFF_DWS);
    float*          dwtT  = (float*)(smem + OFF_DWT);

    const int b    = blockIdx.x;
    const int tid  = threadIdx.x;
    const int w    = tid >> 6;
    const int li   = tid & 15;
    const int quad = (tid >> 4) & 3;

    // ---- init: zero ALL of LDS (pads must be exactly 0 for MFMA k-padding) ----
    for (int t = tid; t < SMEM_BYTES / 4; t += 1024) ((unsigned int*)smem)[t] = 0u;
    __syncthreads();
    // feat = bf16(x chunk 0), layout [n][72c]
    for (int t = tid; t < VD * NQ; t += 1024) {
        int n = t % NQ, c = t / NQ;
        featU[n * 72 + c] = f2bf(x[((size_t)b * DIM + c) * NQ + n]);
    }
    __syncthreads();

    for (int h = 0; h < HEADS; ++h) {
        // ---- prologue: fold BN into (s,t) tables ----
        if (tid < 96) {
            float s = qkv_g[h * 96 + tid] * rsqrtf(qkv_rv[h * 96 + tid] + 1e-5f);
            sbT[tid] = s;
            tbT[tid] = qkv_b[h * 96 + tid] - qkv_rm[h * 96 + tid] * s;
        } else if (tid < 112) {
            int c = tid - 96;
            float s = dw_g[h * 16 + c] * rsqrtf(dw_rv[h * 16 + c] + 1e-5f);
            dwsT[c] = s;
            dwtT[c] = dw_b[h * 16 + c] - dw_rm[h * 16 + c] * s;
        }
        __syncthreads();

        // ---- phase B: QKV = W(hi+lo) x feat(bf16), MFMA, folded BN ----
        // tiles: 6 o-tiles x 13 n-tiles = 78
        for (int T = w; T < 78; T += 16) {
            int ot = T / 13, nt = T - ot * 13;
            const float* wrow = qkv_w + ((size_t)h * 96 + ot * 16 + li) * 64;
            short8 ah0, al0, ah1, al1;
            split8(wrow + quad * 8, ah0, al0);
            split8(wrow + 32 + quad * 8, ah1, al1);
            short8 b0 = *(const short8*)(featU + (nt * 16 + li) * 72 + quad * 8);
            short8 b1 = *(const short8*)(featU + (nt * 16 + li) * 72 + 32 + quad * 8);
            f32x4 acc = {0.f, 0.f, 0.f, 0.f};
            acc = MFMA16(ah0, b0, acc);
            acc = MFMA16(al0, b0, acc);
            acc = MFMA16(ah1, b1, acc);
            acc = MFMA16(al1, b1, acc);
            int n = nt * 16 + li;
            bool nok = (n < NQ);
            #pragma unroll
            for (int r = 0; r < 4; ++r) {
                int o = ot * 16 + quad * 4 + r;
                float val = acc[r] * sbT[o] + tbT[o];
                if (nok) {
                    if (o < 16) {
                        qraw[o * 208 + n] = val;
                    } else if (o < 32) {
                        int c = o - 16;
                        unsigned short hh = f2bf(val);
                        kbH[n * 40 + c] = hh;
                        kbL[n * 40 + c] = f2bf(val - bf2f(hh));
                    } else {
                        int d = o - 32;
                        unsigned short hh = f2bf(val);
                        vbH[d * 232 + n] = hh;
                        vbL[d * 232 + n] = f2bf(val - bf2f(hh));
                    }
                }
            }
        }
        __syncthreads();

        // ---- phase C: depthwise 5x5 conv + BN + *0.25, write qc hi/lo; zero pads ----
        for (int t = tid; t < KD * NQ; t += 1024) {
            int n = t % NQ, c = t / NQ;
            int py = n / 14, px = n - py * 14;
            const float* qr = qraw + c * 208;
            const float* wdc = dw_w + ((size_t)h * KD + c) * 25;
            float accv = 0.f;
            #pragma unroll
            for (int ky = 0; ky < 5; ++ky) {
                int yy = py + ky - 2;
                if (yy < 0 || yy >= 14) continue;
                #pragma unroll
                for (int kx = 0; kx < 5; ++kx) {
                    int xx = px + kx - 2;
                    if (xx < 0 || xx >= 14) continue;
                    accv = fmaf(wdc[ky * 5 + kx], qr[yy * 14 + xx], accv);
                }
            }
            float val = fmaf(accv, dwsT[c], dwtT[c]) * 0.25f;
            unsigned short hh = f2bf(val);
            qcH[n * 40 + c] = hh;
            qcL[n * 40 + c] = f2bf(val - bf2f(hh));
            // re-zero k-pad cols 16..31 (dirtied by feat overlay)
            qcH[n * 40 + 16 + c] = 0;
            qcL[n * 40 + 16 + c] = 0;
        }
        if (tid < 832) den4[tid] = 0.f;
        __syncthreads();

        // ---- phase D: attention. m-loop over 7 tiles of 32 keys ----
        f32x4 pacc[4];
        #pragma unroll
        for (int s = 0; s < 4; ++s) pacc[s] = (f32x4){0.f, 0.f, 0.f, 0.f};

        for (int mi = 0; mi < 7; ++mi) {
            // S-pass: 26 tiles (13 n-tiles x 2 m-subtiles); S = Q(hi+lo) x K(hi+lo), drop lo*lo
            for (int T = w; T < 26; T += 16) {
                int s = (T >= 13) ? 1 : 0;
                int nt = T - s * 13;
                int n0 = nt * 16;
                int mg = mi * 32 + s * 16 + li;       // global key index (= kb row)
                float bias4[4];
                #pragma unroll
                for (int r = 0; r < 4; ++r) {
                    int n = n0 + quad * 4 + r;
                    int ni = n < NQ ? n : NQ - 1;
                    int mgi = mg < NQ ? mg : NQ - 1;
                    bias4[r] = biasg[(size_t)h * (NQ * NQ) + ni * NQ + mgi];
                }
                short8 qh = *(const short8*)(qcH + (n0 + li) * 40 + quad * 8);
                short8 ql = *(const short8*)(qcL + (n0 + li) * 40 + quad * 8);
                short8 kh = *(const short8*)(kbH + mg * 40 + quad * 8);
                short8 kl = *(const short8*)(kbL + mg * 40 + quad * 8);
                f32x4 acc = {0.f, 0.f, 0.f, 0.f};
                acc = MFMA16(qh, kh, acc);
                acc = MFMA16(qh, kl, acc);
                acc = MFMA16(ql, kh, acc);
                bool mok = (mg < NQ);
                #pragma unroll
                for (int r = 0; r < 4; ++r) {
                    float e = mok ? __expf(acc[r] + bias4[r]) : 0.f;
                    int n = n0 + quad * 4 + r;
                    Pb[n * 40 + s * 16 + li] = f2bf(e);
                }
            }
            __syncthreads();

            // den-pass: accumulate row sums of the *bf16* P actually fed to MFMA
            if (tid < 832) {
                int n = tid >> 2, part = tid & 3;
                short8 pv = *(const short8*)(Pb + n * 40 + part * 8);
                float sum = 0.f;
                #pragma unroll
                for (int j = 0; j < 8; ++j) sum += bf2f((unsigned short)pv[j]);
                den4[n * 4 + part] += sum;
            }
            // PV: out += P x V(hi+lo); 52 tiles (13 n x 4 d), K=32 per m-iter
            {
                int slot = 0;
                for (int T = w; T < 52; T += 16, ++slot) {
                    int dt = T / 13, nt = T - dt * 13;
                    short8 p  = *(const short8*)(Pb + (nt * 16 + li) * 40 + quad * 8);
                    short8 vh = *(const short8*)(vbH + (dt * 16 + li) * 232 + mi * 32 + quad * 8);
                    short8 vl = *(const short8*)(vbL + (dt * 16 + li) * 232 + mi * 32 + quad * 8);
                    pacc[slot] = MFMA16(p, vh, pacc[slot]);
                    pacc[slot] = MFMA16(p, vl, pacc[slot]);
                }
            }
            __syncthreads();
        }

        // ---- PV epilogue: normalize, write new feat (bf16) ----
        {
            int slot = 0;
            for (int T = w; T < 52; T += 16, ++slot) {
                int dt = T / 13, nt = T - dt * 13;
                int d = dt * 16 + li;
                #pragma unroll
                for (int r = 0; r < 4; ++r) {
                    int n = nt * 16 + quad * 4 + r;
                    if (n < NQ) {
                        f32x4 dv = *(const f32x4*)(den4 + n * 4);
                        float dn = (dv.x + dv.y) + (dv.z + dv.w);
                        float val = pacc[slot][r] / dn;
                        featU[n * 72 + d] = f2bf(val);
                    }
                }
            }
        }
        __syncthreads();

        // ---- yrelu write: vectorized short8, layout [b*NQ + n][256] ----
        for (int t = tid; t < (VD * NQ) / 8; t += 1024) {
            int n  = t >> 3;
            int c0 = (t & 7) * 8;
            short8 u = *(const short8*)(featU + n * 72 + c0);
            short8 ru;
            #pragma unroll
            for (int j = 0; j < 8; ++j) {
                unsigned short uu = (unsigned short)u[j];
                ru[j] = (short)((uu & 0x8000u) ? (unsigned short)0 : uu);
            }
            *(short8*)(yrelu + ((size_t)b * NQ + n) * DIM + h * VD + c0) = ru;
        }
        __syncthreads();

        // ---- cascade add for next head (x reads stay n-fastest = coalesced) ----
        if (h < 3) {
            for (int t = tid; t < VD * NQ; t += 1024) {
                int n = t % NQ, c = t / NQ;
                float v = bf2f(featU[n * 72 + c]) + x[((size_t)b * DIM + (h + 1) * VD + c) * NQ + n];
                featU[n * 72 + c] = f2bf(v);
            }
            // re-zero feat pad rows 196..207 (dirtied by qc overlay)
            for (int t = tid; t < 12 * 64; t += 1024)
                featU[(NQ + t / 64) * 72 + (t & 63)] = 0;
        }
        __syncthreads();
    }
}

// -------------------- kernel 2: projection GEMM (MFMA) + folded BN ----------------
// Restructured: each block computes ALL 256 outputs for 128 j-rows -> X read
// exactly once (51 MB total). X staged per K-step into double-buffered LDS
// (pad stride 40 -> 2-way conflicts only). One barrier per K-step; next tile's
// global load issued before the MFMA cluster (issue-early / write-late).
// block: 512 thr (8 waves). wave w owns o = [w*32, w*32+32), all 8 j-tiles.
__global__ __launch_bounds__(512, 4)
void proj_kernel(const unsigned short* __restrict__ X,  // yrelu bf16 [B*NQ][256]
                 const float* __restrict__ W,           // [256][256] (o,c)
                 const float* __restrict__ pg,
                 const float* __restrict__ pb,
                 const float* __restrict__ prm,
                 const float* __restrict__ prv,
                 float* __restrict__ out) {
    __shared__ __align__(16) unsigned short Xs[2][128 * 40];  // 2 x 10240 B
    const int tid  = threadIdx.x;
    const int w    = tid >> 6;
    const int li   = tid & 15;
    const int quad = (tid >> 4) & 3;
    const int jb   = blockIdx.x * 128;

    // staging: thread t loads 16 B: row jl = t>>2, cols c0 = (t&3)*8
    const int jl = tid >> 2;
    const int c0 = (tid & 3) * 8;
    const unsigned short* xsrc = X + (size_t)(jb + jl) * 256 + c0;

    f32x4 acc[2][8];
    #pragma unroll
    for (int ot = 0; ot < 2; ++ot)
        #pragma unroll
        for (int jt = 0; jt < 8; ++jt) acc[ot][jt] = (f32x4){0.f, 0.f, 0.f, 0.f};

    // prologue: stage ks=0 into buf 0
    *(short8*)(&Xs[0][jl * 40 + c0]) = *(const short8*)(xsrc);
    __syncthreads();

    const float* wr0 = W + (size_t)(w * 32 + li) * 256 + quad * 8;
    const float* wr1 = wr0 + 16 * 256;

    for (int ks = 0; ks < 8; ++ks) {
        const int cur = ks & 1;
        short8 nv;
        if (ks < 7) nv = *(const short8*)(xsrc + (ks + 1) * 32);  // issue early
        short8 ah0, al0, ah1, al1;
        split8(wr0 + ks * 32, ah0, al0);
        split8(wr1 + ks * 32, ah1, al1);
        #pragma unroll
        for (int jt = 0; jt < 8; ++jt) {
            short8 bx = *(const short8*)(&Xs[cur][(jt * 16 + li) * 40 + quad * 8]);
            acc[0][jt] = MFMA16(ah0, bx, acc[0][jt]);
            acc[0][jt] = MFMA16(al0, bx, acc[0][jt]);
            acc[1][jt] = MFMA16(ah1, bx, acc[1][jt]);
            acc[1][jt] = MFMA16(al1, bx, acc[1][jt]);
        }
        if (ks < 7) {
            *(short8*)(&Xs[cur ^ 1][jl * 40 + c0]) = nv;  // write late
            __syncthreads();
        }
    }

    // epilogue: BN + store fp32 (output stays [b][o][n])
    #pragma unroll
    for (int ot = 0; ot < 2; ++ot) {
        #pragma unroll
        for (int r = 0; r < 4; ++r) {
            int o = w * 32 + ot * 16 + quad * 4 + r;
            float s = pg[o] * rsqrtf(prv[o] + 1e-5f);
            float t = pb[o] - prm[o] * s;
            #pragma unroll
            for (int jt = 0; jt < 8; ++jt) {
                int j = jb + jt * 16 + li;
                int bb = j / NQ;
                int n = j - bb * NQ;
                out[(size_t)bb * CHW + (size_t)o * NQ + n] = fmaf(acc[ot][jt][r], s, t);
            }
        }
    }
}

// -------------------- launch --------------------
extern "C" void kernel_launch(void* const* d_in, const int* in_sizes, int n_in,
                              void* d_out, int out_size, void* d_ws, size_t ws_size,
                              hipStream_t stream) {
    const float* x        = (const float*)d_in[0];
    const float* qkv_w    = (const float*)d_in[1];
    const float* qkv_g    = (const float*)d_in[2];
    const float* qkv_b    = (const float*)d_in[3];
    const float* qkv_rm   = (const float*)d_in[4];
    const float* qkv_rv   = (const float*)d_in[5];
    const float* dw_w     = (const float*)d_in[6];
    const float* dw_g     = (const float*)d_in[7];
    const float* dw_b     = (const float*)d_in[8];
    const float* dw_rm    = (const float*)d_in[9];
    const float* dw_rv    = (const float*)d_in[10];
    const float* proj_w   = (const float*)d_in[11];
    const float* proj_g   = (const float*)d_in[12];
    const float* proj_b   = (const float*)d_in[13];
    const float* proj_rm  = (const float*)d_in[14];
    const float* proj_rv  = (const float*)d_in[15];
    const float* attn_bs  = (const float*)d_in[16];
    const int*   bias_idx = (const int*)d_in[17];

    float* biasg = (float*)d_ws;                                   // 153664 fp32
    unsigned short* yrelu = (unsigned short*)((char*)d_ws + 614656); // B*NQ*DIM bf16, [j][c]

    {
        int total = HEADS * NQ * NQ;
        hipLaunchKernelGGL(bias_expand_kernel, dim3((total + 255) / 256), dim3(256),
                           0, stream, attn_bs, bias_idx, biasg);
    }
    hipLaunchKernelGGL(cascade_attn_kernel, dim3(BATCH), dim3(1024),
                       SMEM_BYTES, stream,
                       x, qkv_w, qkv_g, qkv_b, qkv_rm, qkv_rv,
                       dw_w, dw_g, dw_b, dw_rm, dw_rv, biasg, yrelu);
    hipLaunchKernelGGL(proj_kernel, dim3(784), dim3(512), 0, stream,
                       yrelu, proj_w, proj_g, proj_b, proj_rm, proj_rv,
                       (float*)d_out);
}